// Round 6
// baseline (850.187 us; speedup 1.0000x reference)
//
#include <hip/hip_runtime.h>
#include <math.h>

// ---------------- MS-SSIM on MI355X, round 6 ----------------
// memset(acc) ; k_l0 ; k_tail ; k_final  (4 stream-ordered nodes)
//  k_l0  : level0, TROWS=16, 1280 blocks (5/CU uniform), 3 strips/wave exact,
//          single residency round. Writes pooled P1 + block-atomic partials.
//  k_tail: levels 1-4 ALL from P1 (S=1/2/4/8 on-the-fly pooling, P2 never
//          materialized; P1 is L3-resident). 840 blocks, one dispatch.
//  k_final: 10 double accumulators -> exact combination formula.

static constexpr int TPB = 256;

#define C1F 0.0001f
#define C2F 0.0009f
#define GW0f 0.12007838f
#define GW1f 0.23388060f
#define GW2f 0.29208204f

__device__ __forceinline__ float bperm(int addr, float v) {
    return __int_as_float(__builtin_amdgcn_ds_bpermute(addr, __float_as_int(v)));
}

// Load one level-row (2 level-cols/lane). S>1: avg-pool SxS blocks of the
// (W*S)-wide source on the fly. Branchless: clamped row * 0/1 mask.
template<int W, int S>
__device__ __forceinline__ void load_row(const float* __restrict__ p1,
                                         const float* __restrict__ p2,
                                         int r, int c0c, float colm,
                                         float& x0, float& x1,
                                         float& z0, float& z1)
{
    constexpr int SRCW = W * S;
    const int rc = min(max(r, 0), W - 1);
    const float m = ((unsigned)r < (unsigned)W) ? colm : 0.f;
    if constexpr (S == 1) {
        const size_t o = (size_t)rc * W + c0c;
        const float2 a = *(const float2*)(p1 + o);
        const float2 b = *(const float2*)(p2 + o);
        x0 = a.x * m; x1 = a.y * m; z0 = b.x * m; z1 = b.y * m;
    } else {
        const float* a0 = p1 + (size_t)rc * S * SRCW + c0c * S;
        const float* b0 = p2 + (size_t)rc * S * SRCW + c0c * S;
        float s0 = 0.f, s1 = 0.f, t0 = 0.f, t1 = 0.f;
        #pragma unroll 1
        for (int j = 0; j < S; ++j) {
            const float* a = a0 + j * SRCW;
            const float* b = b0 + j * SRCW;
            if constexpr (S == 2) {
                const float4 A = *(const float4*)a;  s0 += A.x + A.y;  s1 += A.z + A.w;
                const float4 B = *(const float4*)b;  t0 += B.x + B.y;  t1 += B.z + B.w;
            } else if constexpr (S == 4) {
                const float4 A0 = *(const float4*)a;
                const float4 A1 = *(const float4*)(a + 4);
                s0 += (A0.x + A0.y) + (A0.z + A0.w);
                s1 += (A1.x + A1.y) + (A1.z + A1.w);
                const float4 B0 = *(const float4*)b;
                const float4 B1 = *(const float4*)(b + 4);
                t0 += (B0.x + B0.y) + (B0.z + B0.w);
                t1 += (B1.x + B1.y) + (B1.z + B1.w);
            } else { // S == 8
                const float4 A0 = *(const float4*)a;
                const float4 A1 = *(const float4*)(a + 4);
                const float4 A2 = *(const float4*)(a + 8);
                const float4 A3 = *(const float4*)(a + 12);
                s0 += ((A0.x + A0.y) + (A0.z + A0.w)) + ((A1.x + A1.y) + (A1.z + A1.w));
                s1 += ((A2.x + A2.y) + (A2.z + A2.w)) + ((A3.x + A3.y) + (A3.z + A3.w));
                const float4 B0 = *(const float4*)b;
                const float4 B1 = *(const float4*)(b + 4);
                const float4 B2 = *(const float4*)(b + 8);
                const float4 B3 = *(const float4*)(b + 12);
                t0 += ((B0.x + B0.y) + (B0.z + B0.w)) + ((B1.x + B1.y) + (B1.z + B1.w));
                t1 += ((B2.x + B2.y) + (B2.z + B2.w)) + ((B3.x + B3.y) + (B3.z + B3.w));
            }
        }
        constexpr float inv = 1.f / (float)(S * S);
        x0 = s0 * inv * m;  x1 = s1 * inv * m;
        z0 = t0 * inv * m;  z1 = t1 * inv * m;
    }
}

#define SSIM_ACC(A,B,Q,P) { \
    const float ab_   = (A)*(B); \
    const float a2b2_ = fmaf((A),(A),(B)*(B)); \
    const float s12_  = fmaf(2.f,(P)-ab_,C2F); \
    const float sden_ = ((Q)-a2b2_)+C2F; \
    const float d1_   = a2b2_+C1F; \
    const float n1_   = fmaf(2.f,ab_,C1F); \
    const float rd_   = __builtin_amdgcn_rcpf(d1_*sden_); \
    accs = fmaf(voutf, n1_*s12_*rd_, accs); \
    accc = fmaf(voutf, s12_*d1_*rd_, accc); }

// One row step. J = IEXPR%5 (static). DO_PREF/DO_POOL_/DO_VERT compile-time.
#define ROW(IEXPR, J, DO_PREF, DO_POOL_, DO_VERT) { \
    constexpr int J_ = (J); \
    constexpr int K0=(J_+1)%5, K1=(J_+2)%5, K2=(J_+3)%5, K3=(J_+4)%5, K4=J_; \
    const int i_ = (IEXPR); \
    const float x0=nx0, x1=nx1, z0=nz0, z1=nz1; \
    if constexpr (DO_PREF) \
        load_row<W,S>(p1, p2, y0 + i_ - 1, c0c, colm, nx0, nx1, nz0, nz1); \
    if constexpr (DO_POOL_ && POOL) { \
        if (voutf != 0.f) { \
            const int r_ = y0 + i_ - 2; \
            const size_t po_ = (size_t)(r_ >> 1) * (W / 2) + (c0 >> 1); \
            q1[po_] = (px0 + px1 + x0 + x1) * 0.25f; \
            q2[po_] = (py0 + py1 + z0 + z1) * 0.25f; } } \
    if constexpr (POOL) { px0=x0; px1=x1; py0=z0; py1=z1; } \
    const float ux0=bperm(upA,x0), ux1=bperm(upA,x1); \
    const float dx0=bperm(dnA,x0), dx1=bperm(dnA,x1); \
    const float uz0=bperm(upA,z0), uz1=bperm(upA,z1); \
    const float dz0=bperm(dnA,z0), dz1=bperm(dnA,z1); \
    const float qu0=fmaf(ux0,ux0,uz0*uz0), qu1=fmaf(ux1,ux1,uz1*uz1); \
    const float qc0=fmaf(x0,x0,z0*z0),     qc1=fmaf(x1,x1,z1*z1); \
    const float qd0=fmaf(dx0,dx0,dz0*dz0), qd1=fmaf(dx1,dx1,dz1*dz1); \
    const float pu0=ux0*uz0, pu1=ux1*uz1; \
    const float pc0=x0*z0,   pc1=x1*z1; \
    const float pd0=dx0*dz0, pd1=dx1*dz1; \
    wa0[J_]=fmaf(GW0f,ux0+dx0,fmaf(GW1f,ux1+x1,GW2f*x0)); \
    wa1[J_]=fmaf(GW0f,ux1+dx1,fmaf(GW1f,x0+dx0,GW2f*x1)); \
    wb0[J_]=fmaf(GW0f,uz0+dz0,fmaf(GW1f,uz1+z1,GW2f*z0)); \
    wb1[J_]=fmaf(GW0f,uz1+dz1,fmaf(GW1f,z0+dz0,GW2f*z1)); \
    wq0[J_]=fmaf(GW0f,qu0+qd0,fmaf(GW1f,qu1+qc1,GW2f*qc0)); \
    wq1[J_]=fmaf(GW0f,qu1+qd1,fmaf(GW1f,qc0+qd0,GW2f*qc1)); \
    wp0[J_]=fmaf(GW0f,pu0+pd0,fmaf(GW1f,pu1+pc1,GW2f*pc0)); \
    wp1[J_]=fmaf(GW0f,pu1+pd1,fmaf(GW1f,pc0+pd0,GW2f*pc1)); \
    if constexpr (DO_VERT) { \
        const float A1_=fmaf(GW0f,wa0[K0]+wa0[K4],fmaf(GW1f,wa0[K1]+wa0[K3],GW2f*wa0[K2])); \
        const float B1_=fmaf(GW0f,wb0[K0]+wb0[K4],fmaf(GW1f,wb0[K1]+wb0[K3],GW2f*wb0[K2])); \
        const float Q1_=fmaf(GW0f,wq0[K0]+wq0[K4],fmaf(GW1f,wq0[K1]+wq0[K3],GW2f*wq0[K2])); \
        const float P1_=fmaf(GW0f,wp0[K0]+wp0[K4],fmaf(GW1f,wp0[K1]+wp0[K3],GW2f*wp0[K2])); \
        SSIM_ACC(A1_,B1_,Q1_,P1_); \
        const float A2_=fmaf(GW0f,wa1[K0]+wa1[K4],fmaf(GW1f,wa1[K1]+wa1[K3],GW2f*wa1[K2])); \
        const float B2_=fmaf(GW0f,wb1[K0]+wb1[K4],fmaf(GW1f,wb1[K1]+wb1[K3],GW2f*wb1[K2])); \
        const float Q2_=fmaf(GW0f,wq1[K0]+wq1[K4],fmaf(GW1f,wq1[K1]+wq1[K3],GW2f*wq1[K2])); \
        const float P2_=fmaf(GW0f,wp1[K0]+wp1[K4],fmaf(GW1f,wp1[K1]+wp1[K3],GW2f*wp1[K2])); \
        SSIM_ACC(A2_,B2_,Q2_,P2_); \
    } }

// One 124-col x TR-row strip of a WxW level; input = (W*S)-wide source pooled
// SxS on the fly. Accumulates SSIM/cs into accs/accc (per lane, float).
template<int W, int S, bool POOL, int TR>
__device__ __forceinline__ void do_strip(const float* __restrict__ img1,
                                         const float* __restrict__ img2,
                                         int strip,
                                         float* __restrict__ pool1,
                                         float* __restrict__ pool2,
                                         float& accs, float& accc)
{
    constexpr int SX  = (W + 123) / 124;
    constexpr int SY  = (W >= TR) ? (W / TR) : 1;
    constexpr int SPP = SX * SY;
    constexpr int SRCW = W * S;

    const int lane  = threadIdx.x & 63;
    const int plane = strip / SPP;
    const int rem   = strip - plane * SPP;
    const int sy    = rem / SX;
    const int sx    = rem - sy * SX;
    const int y0  = sy * TR;
    const int c0  = sx * 124 - 2 + 2 * lane;
    const int c0c = min(max(c0, 0), W - 2);
    const float colm  = ((unsigned)c0 < (unsigned)W) ? 1.f : 0.f;
    const float voutf = (colm != 0.f && lane >= 1 && lane <= 62) ? 1.f : 0.f;
    const int upA = ((lane + 63) & 63) << 2;
    const int dnA = ((lane + 1) & 63) << 2;

    const float* p1 = img1 + (size_t)plane * SRCW * SRCW;
    const float* p2 = img2 + (size_t)plane * SRCW * SRCW;
    float* q1 = nullptr; float* q2 = nullptr;
    if constexpr (POOL) {
        q1 = pool1 + (size_t)plane * (W / 2) * (W / 2);
        q2 = pool2 + (size_t)plane * (W / 2) * (W / 2);
    }

    float wa0[5], wa1[5], wb0[5], wb1[5], wq0[5], wq1[5], wp0[5], wp1[5];
    float px0 = 0.f, px1 = 0.f, py0 = 0.f, py1 = 0.f;
    float nx0, nx1, nz0, nz1;
    load_row<W,S>(p1, p2, y0 - 2, c0c, colm, nx0, nx1, nz0, nz1);

    // prologue rows 0..4 (first SSIM out at i=4; first pool pair at i=3)
    ROW(0, 0, 1, 0, 0)
    ROW(1, 1, 1, 0, 0)
    ROW(2, 2, 1, 0, 0)
    ROW(3, 3, 1, 1, 0)
    ROW(4, 4, 1, 0, 1)
    if constexpr (TR == 32) {
        // steady rows 5..34 (10-row body keeps J and pool parity static)
        #pragma unroll 1
        for (int i0 = 5; i0 <= 25; i0 += 10) {
            ROW(i0 + 0, 0, 1, 1, 1)
            ROW(i0 + 1, 1, 1, 0, 1)
            ROW(i0 + 2, 2, 1, 1, 1)
            ROW(i0 + 3, 3, 1, 0, 1)
            ROW(i0 + 4, 4, 1, 1, 1)
            ROW(i0 + 5, 0, 1, 0, 1)
            ROW(i0 + 6, 1, 1, 1, 1)
            ROW(i0 + 7, 2, 1, 0, 1)
            ROW(i0 + 8, 3, 1, 1, 1)
            ROW(i0 + 9, 4, 1, 0, 1)
        }
        ROW(35, 0, 0, 0, 1)
    } else {
        // TR == 16: rows 5..14 then epilogue 15..19
        ROW(5,  0, 1, 1, 1)
        ROW(6,  1, 1, 0, 1)
        ROW(7,  2, 1, 1, 1)
        ROW(8,  3, 1, 0, 1)
        ROW(9,  4, 1, 1, 1)
        ROW(10, 0, 1, 0, 1)
        ROW(11, 1, 1, 1, 1)
        ROW(12, 2, 1, 0, 1)
        ROW(13, 3, 1, 1, 1)
        ROW(14, 4, 1, 0, 1)
        ROW(15, 0, 1, 1, 1)
        ROW(16, 1, 1, 0, 1)
        ROW(17, 2, 1, 1, 1)
        ROW(18, 3, 1, 0, 1)
        ROW(19, 4, 0, 0, 1)
    }
}

// block reduce (4 waves) + one double atomicAdd pair. Caller guarantees all
// threads of the block reach this (branches are uniform per block).
#define REDUCE_ATOMIC(ACC2) { \
    float rs = accs, rc = accc; \
    _Pragma("unroll") \
    for (int o = 32; o > 0; o >>= 1) { \
        rs += __shfl_down(rs, o, 64); \
        rc += __shfl_down(rc, o, 64); \
    } \
    const int lane_ = threadIdx.x & 63, wv_ = threadIdx.x >> 6; \
    if (lane_ == 0) { s_part[wv_][0] = rs; s_part[wv_][1] = rc; } \
    __syncthreads(); \
    if (threadIdx.x == 0) { \
        atomicAdd(&(ACC2)[0], (double)(s_part[0][0]+s_part[1][0]+s_part[2][0]+s_part[3][0])); \
        atomicAdd(&(ACC2)[1], (double)(s_part[0][1]+s_part[1][1]+s_part[2][1]+s_part[3][1])); \
    } }

// level 0: 15360 strips (TR=16), 1280 blocks = 5/CU, 3 strips/wave exact.
__global__ __launch_bounds__(TPB, 5)
void k_l0(const float* __restrict__ img1, const float* __restrict__ img2,
          float* __restrict__ P1a, float* __restrict__ P1b,
          double* __restrict__ acc)
{
    __shared__ float s_part[4][2];
    const int gw = blockIdx.x * 4 + (threadIdx.x >> 6);   // 0..5119
    float accs = 0.f, accc = 0.f;
    #pragma unroll 1
    for (int s = gw; s < 15360; s += 5120)
        do_strip<512, 1, true, 16>(img1, img2, s, P1a, P1b, accs, accc);
    REDUCE_ATOMIC(acc + 0)
}

// levels 1-4, all from P1 (256-wide): 2304+768+192+96 strips (TR=32), 840 blocks
__global__ __launch_bounds__(TPB, 4)
void k_tail(const float* __restrict__ P1a, const float* __restrict__ P1b,
            double* __restrict__ acc)
{
    __shared__ float s_part[4][2];
    const int wv = threadIdx.x >> 6;
    const int b = blockIdx.x;
    float accs = 0.f, accc = 0.f;
    if (b < 576) {               // level 1: W=256, S=1
        do_strip<256, 1, false, 32>(P1a, P1b, b * 4 + wv, nullptr, nullptr, accs, accc);
        REDUCE_ATOMIC(acc + 2)
    } else if (b < 768) {        // level 2: W=128, S=2
        do_strip<128, 2, false, 32>(P1a, P1b, (b - 576) * 4 + wv, nullptr, nullptr, accs, accc);
        REDUCE_ATOMIC(acc + 4)
    } else if (b < 816) {        // level 3: W=64, S=4
        do_strip<64, 4, false, 32>(P1a, P1b, (b - 768) * 4 + wv, nullptr, nullptr, accs, accc);
        REDUCE_ATOMIC(acc + 6)
    } else {                     // level 4: W=32, S=8
        do_strip<32, 8, false, 32>(P1a, P1b, (b - 816) * 4 + wv, nullptr, nullptr, accs, accc);
        REDUCE_ATOMIC(acc + 8)
    }
}

__global__ void k_final(const double* __restrict__ acc, float* __restrict__ out)
{
    if (threadIdx.x == 0) {
        const double w[5]   = {0.0448, 0.2856, 0.3001, 0.2363, 0.1333};
        const double npx[5] = {96.0*512*512, 96.0*256*256, 96.0*128*128,
                               96.0*64*64,   96.0*32*32};
        double lvl[5][2];
        for (int l = 0; l < 5; ++l) {
            lvl[l][0] = acc[2*l]   / npx[l];
            lvl[l][1] = acc[2*l+1] / npx[l];
        }
        double ssim4 = (lvl[4][0] + 1.0) * 0.5;
        double P = pow(ssim4, w[4]);
        double r = pow((lvl[0][1] + 1.0) * 0.5, w[0]) *
                   pow((lvl[1][1] + 1.0) * 0.5, w[1]) *
                   pow((lvl[2][1] + 1.0) * 0.5, w[2]) *
                   pow((lvl[3][1] + 1.0) * 0.5, w[3]);
        r *= P * P * P * P;
        out[0] = (float)r;
    }
}

extern "C" void kernel_launch(void* const* d_in, const int* in_sizes, int n_in,
                              void* d_out, int out_size, void* d_ws, size_t ws_size,
                              hipStream_t stream)
{
    const float* img1 = (const float*)d_in[0];
    const float* img2 = (const float*)d_in[1];
    float* out = (float*)d_out;

    char* ws = (char*)d_ws;
    double* acc = (double*)ws;                  // 10 doubles used
    float* P1a = (float*)(ws + 256);            // 96*256*256 floats each
    float* P1b = P1a + (size_t)96 * 256 * 256;

    hipMemsetAsync(acc, 0, 16 * sizeof(double), stream);
    k_l0  <<<1280, TPB, 0, stream>>>(img1, img2, P1a, P1b, acc);
    k_tail<<<840,  TPB, 0, stream>>>(P1a, P1b, acc);
    k_final<<<1, 64, 0, stream>>>(acc, out);
}

// Round 8
// 446.095 us; speedup vs baseline: 1.9058x; 1.9058x over previous
//
#include <hip/hip_runtime.h>
#include <math.h>

// ---------------- MS-SSIM on MI355X, round 7 (resubmit; R7 bench hit a
// GPU-broker timeout, no data) ----------------
// R6 structure with the fatal __launch_bounds__ register cap REMOVED (R6's
// (256,5) forced VGPR 84->48 => 800 MB scratch spill traffic, 2x regression).
// Natural allocation (~84 VGPR) gives 6 blocks/CU capacity; k_l0's grid of
// 1280 (5/CU) is already single-round without any cap.
//  memset(acc) ; k_l0 ; k_tail ; k_final
//  k_l0  : level0, TR=16, 15360 strips, 1280 blocks, 3 strips/wave exact,
//          writes pooled P1 + block-atomic double partials.
//  k_tail: levels 1-4 ALL from P1 (S=1/2/4/8 on-the-fly pooling), 840 blocks.
//  k_final: 10 double accumulators -> exact combination formula.

static constexpr int TPB = 256;

#define C1F 0.0001f
#define C2F 0.0009f
#define GW0f 0.12007838f
#define GW1f 0.23388060f
#define GW2f 0.29208204f

__device__ __forceinline__ float bperm(int addr, float v) {
    return __int_as_float(__builtin_amdgcn_ds_bpermute(addr, __float_as_int(v)));
}

// Load one level-row (2 level-cols/lane). S>1: avg-pool SxS blocks of the
// (W*S)-wide source on the fly. Branchless: clamped row * 0/1 mask.
template<int W, int S>
__device__ __forceinline__ void load_row(const float* __restrict__ p1,
                                         const float* __restrict__ p2,
                                         int r, int c0c, float colm,
                                         float& x0, float& x1,
                                         float& z0, float& z1)
{
    constexpr int SRCW = W * S;
    const int rc = min(max(r, 0), W - 1);
    const float m = ((unsigned)r < (unsigned)W) ? colm : 0.f;
    if constexpr (S == 1) {
        const size_t o = (size_t)rc * W + c0c;
        const float2 a = *(const float2*)(p1 + o);
        const float2 b = *(const float2*)(p2 + o);
        x0 = a.x * m; x1 = a.y * m; z0 = b.x * m; z1 = b.y * m;
    } else {
        const float* a0 = p1 + (size_t)rc * S * SRCW + c0c * S;
        const float* b0 = p2 + (size_t)rc * S * SRCW + c0c * S;
        float s0 = 0.f, s1 = 0.f, t0 = 0.f, t1 = 0.f;
        #pragma unroll 1
        for (int j = 0; j < S; ++j) {
            const float* a = a0 + j * SRCW;
            const float* b = b0 + j * SRCW;
            if constexpr (S == 2) {
                const float4 A = *(const float4*)a;  s0 += A.x + A.y;  s1 += A.z + A.w;
                const float4 B = *(const float4*)b;  t0 += B.x + B.y;  t1 += B.z + B.w;
            } else if constexpr (S == 4) {
                const float4 A0 = *(const float4*)a;
                const float4 A1 = *(const float4*)(a + 4);
                s0 += (A0.x + A0.y) + (A0.z + A0.w);
                s1 += (A1.x + A1.y) + (A1.z + A1.w);
                const float4 B0 = *(const float4*)b;
                const float4 B1 = *(const float4*)(b + 4);
                t0 += (B0.x + B0.y) + (B0.z + B0.w);
                t1 += (B1.x + B1.y) + (B1.z + B1.w);
            } else { // S == 8
                const float4 A0 = *(const float4*)a;
                const float4 A1 = *(const float4*)(a + 4);
                const float4 A2 = *(const float4*)(a + 8);
                const float4 A3 = *(const float4*)(a + 12);
                s0 += ((A0.x + A0.y) + (A0.z + A0.w)) + ((A1.x + A1.y) + (A1.z + A1.w));
                s1 += ((A2.x + A2.y) + (A2.z + A2.w)) + ((A3.x + A3.y) + (A3.z + A3.w));
                const float4 B0 = *(const float4*)b;
                const float4 B1 = *(const float4*)(b + 4);
                const float4 B2 = *(const float4*)(b + 8);
                const float4 B3 = *(const float4*)(b + 12);
                t0 += ((B0.x + B0.y) + (B0.z + B0.w)) + ((B1.x + B1.y) + (B1.z + B1.w));
                t1 += ((B2.x + B2.y) + (B2.z + B2.w)) + ((B3.x + B3.y) + (B3.z + B3.w));
            }
        }
        constexpr float inv = 1.f / (float)(S * S);
        x0 = s0 * inv * m;  x1 = s1 * inv * m;
        z0 = t0 * inv * m;  z1 = t1 * inv * m;
    }
}

#define SSIM_ACC(A,B,Q,P) { \
    const float ab_   = (A)*(B); \
    const float a2b2_ = fmaf((A),(A),(B)*(B)); \
    const float s12_  = fmaf(2.f,(P)-ab_,C2F); \
    const float sden_ = ((Q)-a2b2_)+C2F; \
    const float d1_   = a2b2_+C1F; \
    const float n1_   = fmaf(2.f,ab_,C1F); \
    const float rd_   = __builtin_amdgcn_rcpf(d1_*sden_); \
    accs = fmaf(voutf, n1_*s12_*rd_, accs); \
    accc = fmaf(voutf, s12_*d1_*rd_, accc); }

// One row step. J = IEXPR%5 (static). DO_PREF/DO_POOL_/DO_VERT compile-time.
#define ROW(IEXPR, J, DO_PREF, DO_POOL_, DO_VERT) { \
    constexpr int J_ = (J); \
    constexpr int K0=(J_+1)%5, K1=(J_+2)%5, K2=(J_+3)%5, K3=(J_+4)%5, K4=J_; \
    const int i_ = (IEXPR); \
    const float x0=nx0, x1=nx1, z0=nz0, z1=nz1; \
    if constexpr (DO_PREF) \
        load_row<W,S>(p1, p2, y0 + i_ - 1, c0c, colm, nx0, nx1, nz0, nz1); \
    if constexpr (DO_POOL_ && POOL) { \
        if (voutf != 0.f) { \
            const int r_ = y0 + i_ - 2; \
            const size_t po_ = (size_t)(r_ >> 1) * (W / 2) + (c0 >> 1); \
            q1[po_] = (px0 + px1 + x0 + x1) * 0.25f; \
            q2[po_] = (py0 + py1 + z0 + z1) * 0.25f; } } \
    if constexpr (POOL) { px0=x0; px1=x1; py0=z0; py1=z1; } \
    const float ux0=bperm(upA,x0), ux1=bperm(upA,x1); \
    const float dx0=bperm(dnA,x0), dx1=bperm(dnA,x1); \
    const float uz0=bperm(upA,z0), uz1=bperm(upA,z1); \
    const float dz0=bperm(dnA,z0), dz1=bperm(dnA,z1); \
    const float qu0=fmaf(ux0,ux0,uz0*uz0), qu1=fmaf(ux1,ux1,uz1*uz1); \
    const float qc0=fmaf(x0,x0,z0*z0),     qc1=fmaf(x1,x1,z1*z1); \
    const float qd0=fmaf(dx0,dx0,dz0*dz0), qd1=fmaf(dx1,dx1,dz1*dz1); \
    const float pu0=ux0*uz0, pu1=ux1*uz1; \
    const float pc0=x0*z0,   pc1=x1*z1; \
    const float pd0=dx0*dz0, pd1=dx1*dz1; \
    wa0[J_]=fmaf(GW0f,ux0+dx0,fmaf(GW1f,ux1+x1,GW2f*x0)); \
    wa1[J_]=fmaf(GW0f,ux1+dx1,fmaf(GW1f,x0+dx0,GW2f*x1)); \
    wb0[J_]=fmaf(GW0f,uz0+dz0,fmaf(GW1f,uz1+z1,GW2f*z0)); \
    wb1[J_]=fmaf(GW0f,uz1+dz1,fmaf(GW1f,z0+dz0,GW2f*z1)); \
    wq0[J_]=fmaf(GW0f,qu0+qd0,fmaf(GW1f,qu1+qc1,GW2f*qc0)); \
    wq1[J_]=fmaf(GW0f,qu1+qd1,fmaf(GW1f,qc0+qd0,GW2f*qc1)); \
    wp0[J_]=fmaf(GW0f,pu0+pd0,fmaf(GW1f,pu1+pc1,GW2f*pc0)); \
    wp1[J_]=fmaf(GW0f,pu1+pd1,fmaf(GW1f,pc0+pd0,GW2f*pc1)); \
    if constexpr (DO_VERT) { \
        const float A1_=fmaf(GW0f,wa0[K0]+wa0[K4],fmaf(GW1f,wa0[K1]+wa0[K3],GW2f*wa0[K2])); \
        const float B1_=fmaf(GW0f,wb0[K0]+wb0[K4],fmaf(GW1f,wb0[K1]+wb0[K3],GW2f*wb0[K2])); \
        const float Q1_=fmaf(GW0f,wq0[K0]+wq0[K4],fmaf(GW1f,wq0[K1]+wq0[K3],GW2f*wq0[K2])); \
        const float P1_=fmaf(GW0f,wp0[K0]+wp0[K4],fmaf(GW1f,wp0[K1]+wp0[K3],GW2f*wp0[K2])); \
        SSIM_ACC(A1_,B1_,Q1_,P1_); \
        const float A2_=fmaf(GW0f,wa1[K0]+wa1[K4],fmaf(GW1f,wa1[K1]+wa1[K3],GW2f*wa1[K2])); \
        const float B2_=fmaf(GW0f,wb1[K0]+wb1[K4],fmaf(GW1f,wb1[K1]+wb1[K3],GW2f*wb1[K2])); \
        const float Q2_=fmaf(GW0f,wq1[K0]+wq1[K4],fmaf(GW1f,wq1[K1]+wq1[K3],GW2f*wq1[K2])); \
        const float P2_=fmaf(GW0f,wp1[K0]+wp1[K4],fmaf(GW1f,wp1[K1]+wp1[K3],GW2f*wp1[K2])); \
        SSIM_ACC(A2_,B2_,Q2_,P2_); \
    } }

// One 124-col x TR-row strip of a WxW level; input = (W*S)-wide source pooled
// SxS on the fly. Accumulates SSIM/cs into accs/accc (per lane, float).
template<int W, int S, bool POOL, int TR>
__device__ __forceinline__ void do_strip(const float* __restrict__ img1,
                                         const float* __restrict__ img2,
                                         int strip,
                                         float* __restrict__ pool1,
                                         float* __restrict__ pool2,
                                         float& accs, float& accc)
{
    constexpr int SX  = (W + 123) / 124;
    constexpr int SY  = (W >= TR) ? (W / TR) : 1;
    constexpr int SPP = SX * SY;
    constexpr int SRCW = W * S;

    const int lane  = threadIdx.x & 63;
    const int plane = strip / SPP;
    const int rem   = strip - plane * SPP;
    const int sy    = rem / SX;
    const int sx    = rem - sy * SX;
    const int y0  = sy * TR;
    const int c0  = sx * 124 - 2 + 2 * lane;
    const int c0c = min(max(c0, 0), W - 2);
    const float colm  = ((unsigned)c0 < (unsigned)W) ? 1.f : 0.f;
    const float voutf = (colm != 0.f && lane >= 1 && lane <= 62) ? 1.f : 0.f;
    const int upA = ((lane + 63) & 63) << 2;
    const int dnA = ((lane + 1) & 63) << 2;

    const float* p1 = img1 + (size_t)plane * SRCW * SRCW;
    const float* p2 = img2 + (size_t)plane * SRCW * SRCW;
    float* q1 = nullptr; float* q2 = nullptr;
    if constexpr (POOL) {
        q1 = pool1 + (size_t)plane * (W / 2) * (W / 2);
        q2 = pool2 + (size_t)plane * (W / 2) * (W / 2);
    }

    float wa0[5], wa1[5], wb0[5], wb1[5], wq0[5], wq1[5], wp0[5], wp1[5];
    float px0 = 0.f, px1 = 0.f, py0 = 0.f, py1 = 0.f;
    float nx0, nx1, nz0, nz1;
    load_row<W,S>(p1, p2, y0 - 2, c0c, colm, nx0, nx1, nz0, nz1);

    // prologue rows 0..4 (first SSIM out at i=4; first pool pair at i=3)
    ROW(0, 0, 1, 0, 0)
    ROW(1, 1, 1, 0, 0)
    ROW(2, 2, 1, 0, 0)
    ROW(3, 3, 1, 1, 0)
    ROW(4, 4, 1, 0, 1)
    if constexpr (TR == 32) {
        // steady rows 5..34 (10-row body keeps J and pool parity static)
        #pragma unroll 1
        for (int i0 = 5; i0 <= 25; i0 += 10) {
            ROW(i0 + 0, 0, 1, 1, 1)
            ROW(i0 + 1, 1, 1, 0, 1)
            ROW(i0 + 2, 2, 1, 1, 1)
            ROW(i0 + 3, 3, 1, 0, 1)
            ROW(i0 + 4, 4, 1, 1, 1)
            ROW(i0 + 5, 0, 1, 0, 1)
            ROW(i0 + 6, 1, 1, 1, 1)
            ROW(i0 + 7, 2, 1, 0, 1)
            ROW(i0 + 8, 3, 1, 1, 1)
            ROW(i0 + 9, 4, 1, 0, 1)
        }
        ROW(35, 0, 0, 0, 1)
    } else {
        // TR == 16: rows 5..14 then epilogue 15..19
        ROW(5,  0, 1, 1, 1)
        ROW(6,  1, 1, 0, 1)
        ROW(7,  2, 1, 1, 1)
        ROW(8,  3, 1, 0, 1)
        ROW(9,  4, 1, 1, 1)
        ROW(10, 0, 1, 0, 1)
        ROW(11, 1, 1, 1, 1)
        ROW(12, 2, 1, 0, 1)
        ROW(13, 3, 1, 1, 1)
        ROW(14, 4, 1, 0, 1)
        ROW(15, 0, 1, 1, 1)
        ROW(16, 1, 1, 0, 1)
        ROW(17, 2, 1, 1, 1)
        ROW(18, 3, 1, 0, 1)
        ROW(19, 4, 0, 0, 1)
    }
}

// block reduce (4 waves) + one double atomicAdd pair. Caller guarantees all
// threads of the block reach this (branches are uniform per block).
#define REDUCE_ATOMIC(ACC2) { \
    float rs = accs, rc = accc; \
    _Pragma("unroll") \
    for (int o = 32; o > 0; o >>= 1) { \
        rs += __shfl_down(rs, o, 64); \
        rc += __shfl_down(rc, o, 64); \
    } \
    const int lane_ = threadIdx.x & 63, wv_ = threadIdx.x >> 6; \
    if (lane_ == 0) { s_part[wv_][0] = rs; s_part[wv_][1] = rc; } \
    __syncthreads(); \
    if (threadIdx.x == 0) { \
        atomicAdd(&(ACC2)[0], (double)(s_part[0][0]+s_part[1][0]+s_part[2][0]+s_part[3][0])); \
        atomicAdd(&(ACC2)[1], (double)(s_part[0][1]+s_part[1][1]+s_part[2][1]+s_part[3][1])); \
    } }

// level 0: 15360 strips (TR=16), 1280 blocks = 5/CU, 3 strips/wave exact.
// NO min-waves bound: natural VGPR (~84) already permits 6 blocks/CU; forcing
// 5 waves/EU in R6 crushed VGPR to 48 and spilled ~800 MB to scratch.
__global__ __launch_bounds__(TPB)
void k_l0(const float* __restrict__ img1, const float* __restrict__ img2,
          float* __restrict__ P1a, float* __restrict__ P1b,
          double* __restrict__ acc)
{
    __shared__ float s_part[4][2];
    const int gw = blockIdx.x * 4 + (threadIdx.x >> 6);   // 0..5119
    float accs = 0.f, accc = 0.f;
    #pragma unroll 1
    for (int s = gw; s < 15360; s += 5120)
        do_strip<512, 1, true, 16>(img1, img2, s, P1a, P1b, accs, accc);
    REDUCE_ATOMIC(acc + 0)
}

// levels 1-4, all from P1 (256-wide): 2304+768+192+96 strips (TR=32), 840 blocks
__global__ __launch_bounds__(TPB)
void k_tail(const float* __restrict__ P1a, const float* __restrict__ P1b,
            double* __restrict__ acc)
{
    __shared__ float s_part[4][2];
    const int wv = threadIdx.x >> 6;
    const int b = blockIdx.x;
    float accs = 0.f, accc = 0.f;
    if (b < 576) {               // level 1: W=256, S=1
        do_strip<256, 1, false, 32>(P1a, P1b, b * 4 + wv, nullptr, nullptr, accs, accc);
        REDUCE_ATOMIC(acc + 2)
    } else if (b < 768) {        // level 2: W=128, S=2
        do_strip<128, 2, false, 32>(P1a, P1b, (b - 576) * 4 + wv, nullptr, nullptr, accs, accc);
        REDUCE_ATOMIC(acc + 4)
    } else if (b < 816) {        // level 3: W=64, S=4
        do_strip<64, 4, false, 32>(P1a, P1b, (b - 768) * 4 + wv, nullptr, nullptr, accs, accc);
        REDUCE_ATOMIC(acc + 6)
    } else {                     // level 4: W=32, S=8
        do_strip<32, 8, false, 32>(P1a, P1b, (b - 816) * 4 + wv, nullptr, nullptr, accs, accc);
        REDUCE_ATOMIC(acc + 8)
    }
}

__global__ void k_final(const double* __restrict__ acc, float* __restrict__ out)
{
    if (threadIdx.x == 0) {
        const double w[5]   = {0.0448, 0.2856, 0.3001, 0.2363, 0.1333};
        const double npx[5] = {96.0*512*512, 96.0*256*256, 96.0*128*128,
                               96.0*64*64,   96.0*32*32};
        double lvl[5][2];
        for (int l = 0; l < 5; ++l) {
            lvl[l][0] = acc[2*l]   / npx[l];
            lvl[l][1] = acc[2*l+1] / npx[l];
        }
        double ssim4 = (lvl[4][0] + 1.0) * 0.5;
        double P = pow(ssim4, w[4]);
        double r = pow((lvl[0][1] + 1.0) * 0.5, w[0]) *
                   pow((lvl[1][1] + 1.0) * 0.5, w[1]) *
                   pow((lvl[2][1] + 1.0) * 0.5, w[2]) *
                   pow((lvl[3][1] + 1.0) * 0.5, w[3]);
        r *= P * P * P * P;
        out[0] = (float)r;
    }
}

extern "C" void kernel_launch(void* const* d_in, const int* in_sizes, int n_in,
                              void* d_out, int out_size, void* d_ws, size_t ws_size,
                              hipStream_t stream)
{
    const float* img1 = (const float*)d_in[0];
    const float* img2 = (const float*)d_in[1];
    float* out = (float*)d_out;

    char* ws = (char*)d_ws;
    double* acc = (double*)ws;                  // 10 doubles used
    float* P1a = (float*)(ws + 256);            // 96*256*256 floats each
    float* P1b = P1a + (size_t)96 * 256 * 256;

    hipMemsetAsync(acc, 0, 16 * sizeof(double), stream);
    k_l0  <<<1280, TPB, 0, stream>>>(img1, img2, P1a, P1b, acc);
    k_tail<<<840,  TPB, 0, stream>>>(P1a, P1b, acc);
    k_final<<<1, 64, 0, stream>>>(acc, out);
}